// Round 8
// baseline (324.233 us; speedup 1.0000x reference)
//
#include <hip/hip_runtime.h>

// NCC loss: five 9x9x9 box sums (I, J, I^2, J^2, I*J), stride 1, pad 4,
// count_include_pad (divisor 729), ncc = cov^2/(varI*varJ+eps), out = -mean.
// Shapes fixed: [2,1,192,192,192] fp32.
//
// R8: y-PAIR decomposition + exact-3 grid + role-split waves.
//  - LDS stores raw x-sum rows R and aligned pair-sums Q[g]=R[2g]+R[2g+1].
//    9-row window at even yA = Q[g0..g0+3]+R[yA+8]; at yA+1 =
//    R[yA+1]+Q[g0+1..g0+4]  -> 7 row-reads per output pair (was 10).
//  - Tile 16x24, KZ=48 -> grid 768 = EXACTLY 3 blocks/CU (864 had a ~19%
//    imbalance tail: 96 CUs got 4 blocks).
//  - Wave role-split: threads 0..191 y-role (rings+emit), 192..255 x-role
//    (2-row pair tasks: 12 float4 global loads, sliding windows, write R,R,Q).
//  - Carried: named-scalar z-rings (spill-proof), LDS-only barrier
//    (s_waitcnt lgkmcnt(0); s_barrier -- keeps global prefetch in flight),
//    XCD swizzle (FETCH == ~compulsory), direct-global x-phase.

#define S    192
#define SS   (S * S)
#define TX   16
#define YT   24
#define NTHR 256
#define KZ   48
#define RAD  4
#define WIN  9
#define NSL  (KZ + 2 * RAD)      // 56
#define HXR  (YT + 2 * RAD)      // 32 halo rows
#define NPAIR (HXR / 2)          // 16 row-pairs
#define XSW  17                  // float4 row stride (R4/Q4)
#define XSW1 20                  // float row stride (R1/Q1)
#define NVOX (2.0 * S * S * S)

// LDS-only barrier: no vmcnt drain -> global prefetch survives.
#define LDS_BARRIER() __asm__ __volatile__("s_waitcnt lgkmcnt(0)\n\ts_barrier" ::: "memory")

__global__ void ncc_init(double* ws) { ws[0] = 0.0; }

__global__ void ncc_final(const double* __restrict__ ws, float* __restrict__ out) {
    out[0] = (float)(-ws[0] / NVOX);
}

__device__ __forceinline__ float4 f4add(float4 a, float4 b) {
    return make_float4(a.x + b.x, a.y + b.y, a.z + b.z, a.w + b.w);
}
__device__ __forceinline__ float4 f4sub(float4 a, float4 b) {
    return make_float4(a.x - b.x, a.y - b.y, a.z - b.z, a.w - b.w);
}

__global__ __launch_bounds__(NTHR, 3) void ncc_main(const float* __restrict__ I,
                                                    const float* __restrict__ J,
                                                    double* __restrict__ ws) {
    // LDS ~33.0 KB: R4 17408 + R1 5120 + Q4 8704 + Q1 2560 + red
    __shared__ float4 R4[2][HXR][XSW];     // raw rows: (sI, sJ, sI2, sJ2)
    __shared__ float  R1[2][HXR][XSW1];    // raw rows: sIJ
    __shared__ float4 Q4[2][NPAIR][XSW];   // pair rows
    __shared__ float  Q1[2][NPAIR][XSW1];
    __shared__ float  red[4];

    const int tid = threadIdx.x;           // 0..255

    // XCD swizzle over 768 blocks (12x8 xy-tiles x 4 z-chunks x 2 batches).
    const int id  = blockIdx.x;            // 0..767
    const int xcd = id & 7;
    const int lo  = id >> 3;               // 0..95
    const int t   = lo % 12;
    const int zb  = lo / 12;               // 0..7
    const int bx  = (xcd & 3) * 3 + t % 3;       // 0..11
    const int by  = (xcd >> 2) * 4 + t / 3;      // 0..7
    const int b   = zb >> 2;
    const int zc  = zb & 3;
    const int x0 = bx * TX, y0 = by * YT, z0 = zc * KZ;

    const float* Ib = I + (size_t)b * S * SS;
    const float* Jb = J + (size_t)b * S * SS;

    // ---- x-role setup (threads 192..255): pair task (g, q) ----
    const bool xrole = (tid >= 192);
    const int  u   = tid - 192;            // 0..63
    const int  pg  = u >> 2;               // pair 0..15
    const int  pq  = u & 3;                // col-quad 0..3
    const int  ra  = 2 * pg;               // halo rows
    const int  rb  = ra + 1;
    const int  gya = y0 - RAD + ra;
    const int  gyb = gya + 1;
    const int  c0  = x0 + 4 * pq - RAD;
    const bool cva = ((unsigned)(c0)     < (unsigned)S);
    const bool cvb = ((unsigned)(c0 + 4) < (unsigned)S);
    const bool cvc = ((unsigned)(c0 + 8) < (unsigned)S);
    const bool rya = xrole && ((unsigned)gya < (unsigned)S);
    const bool ryb = xrole && ((unsigned)gyb < (unsigned)S);
    const ptrdiff_t offa = rya ? ((ptrdiff_t)gya * S + c0) : 0;
    const ptrdiff_t offb = ryb ? ((ptrdiff_t)gyb * S + c0) : 0;

    float4 ia0, ia1, ia2, ja0, ja1, ja2;   // row ra staging
    float4 ib0, ib1, ib2, jb0, jb1, jb2;   // row rb staging

    auto LOAD = [&](int p) {
        const float4 Z = make_float4(0.f, 0.f, 0.f, 0.f);
        ia0 = ia1 = ia2 = ja0 = ja1 = ja2 = Z;
        ib0 = ib1 = ib2 = jb0 = jb1 = jb2 = Z;
        if (xrole && p < NSL) {
            const int zi = z0 - RAD + p;
            if ((unsigned)zi < (unsigned)S) {
                const float* pI = Ib + (size_t)zi * SS;
                const float* pJ = Jb + (size_t)zi * SS;
                if (rya) {
                    const float* rI = pI + offa;
                    const float* rJ = pJ + offa;
                    if (cva) { ia0 = *(const float4*)(rI);     ja0 = *(const float4*)(rJ); }
                    if (cvb) { ia1 = *(const float4*)(rI + 4); ja1 = *(const float4*)(rJ + 4); }
                    if (cvc) { ia2 = *(const float4*)(rI + 8); ja2 = *(const float4*)(rJ + 8); }
                }
                if (ryb) {
                    const float* rI = pI + offb;
                    const float* rJ = pJ + offb;
                    if (cva) { ib0 = *(const float4*)(rI);     jb0 = *(const float4*)(rJ); }
                    if (cvb) { ib1 = *(const float4*)(rI + 4); jb1 = *(const float4*)(rJ + 4); }
                    if (cvc) { ib2 = *(const float4*)(rI + 8); jb2 = *(const float4*)(rJ + 8); }
                }
            }
        }
    };

    auto XPHASE = [&](int p) {
        if (xrole) {
            const float iva[12] = { ia0.x, ia0.y, ia0.z, ia0.w,
                                    ia1.x, ia1.y, ia1.z, ia1.w,
                                    ia2.x, ia2.y, ia2.z, ia2.w };
            const float jva[12] = { ja0.x, ja0.y, ja0.z, ja0.w,
                                    ja1.x, ja1.y, ja1.z, ja1.w,
                                    ja2.x, ja2.y, ja2.z, ja2.w };
            const float ivb[12] = { ib0.x, ib0.y, ib0.z, ib0.w,
                                    ib1.x, ib1.y, ib1.z, ib1.w,
                                    ib2.x, ib2.y, ib2.z, ib2.w };
            const float jvb[12] = { jb0.x, jb0.y, jb0.z, jb0.w,
                                    jb1.x, jb1.y, jb1.z, jb1.w,
                                    jb2.x, jb2.y, jb2.z, jb2.w };
            float A0 = 0.f, B0 = 0.f, C0 = 0.f, D0 = 0.f, E0 = 0.f;
            float A1 = 0.f, B1 = 0.f, C1 = 0.f, D1 = 0.f, E1 = 0.f;
            #pragma unroll
            for (int m = 0; m < WIN; ++m) {
                A0 += iva[m];  B0 += jva[m];
                C0 = fmaf(iva[m], iva[m], C0);
                D0 = fmaf(jva[m], jva[m], D0);
                E0 = fmaf(iva[m], jva[m], E0);
                A1 += ivb[m];  B1 += jvb[m];
                C1 = fmaf(ivb[m], ivb[m], C1);
                D1 = fmaf(jvb[m], jvb[m], D1);
                E1 = fmaf(ivb[m], jvb[m], E1);
            }
            const int cb = p & 1;
            #pragma unroll
            for (int k = 0; k < 4; ++k) {
                if (k > 0) {
                    A0 += iva[8 + k] - iva[k - 1];
                    B0 += jva[8 + k] - jva[k - 1];
                    C0 += fmaf(iva[8 + k], iva[8 + k], -iva[k - 1] * iva[k - 1]);
                    D0 += fmaf(jva[8 + k], jva[8 + k], -jva[k - 1] * jva[k - 1]);
                    E0 += fmaf(iva[8 + k], jva[8 + k], -iva[k - 1] * jva[k - 1]);
                    A1 += ivb[8 + k] - ivb[k - 1];
                    B1 += jvb[8 + k] - jvb[k - 1];
                    C1 += fmaf(ivb[8 + k], ivb[8 + k], -ivb[k - 1] * ivb[k - 1]);
                    D1 += fmaf(jvb[8 + k], jvb[8 + k], -jvb[k - 1] * jvb[k - 1]);
                    E1 += fmaf(ivb[8 + k], jvb[8 + k], -ivb[k - 1] * jvb[k - 1]);
                }
                const int cc = 4 * pq + k;
                R4[cb][ra][cc] = make_float4(A0, B0, C0, D0);
                R1[cb][ra][cc] = E0;
                R4[cb][rb][cc] = make_float4(A1, B1, C1, D1);
                R1[cb][rb][cc] = E1;
                Q4[cb][pg][cc] = make_float4(A0 + A1, B0 + B1, C0 + C1, D0 + D1);
                Q1[cb][pg][cc] = E0 + E1;
            }
        }
    };

    // ---- y-role setup (threads 0..191): outputs yA, yA+1 ----
    const bool yrole = (tid < 192);
    const int  tx  = tid & 15;
    const int  tyt = tid >> 4;             // 0..11 valid for y-role
    const int  yA  = 2 * tyt;

    // z-rings as NAMED scalars (spill-proof; R6/R7-proven).
    const float4 F40 = make_float4(0.f, 0.f, 0.f, 0.f);
    float4 a4_0 = F40, a4_1 = F40, a4_2 = F40, a4_3 = F40, a4_4 = F40,
           a4_5 = F40, a4_6 = F40, a4_7 = F40, a4_8 = F40;
    float  a1_0 = 0.f, a1_1 = 0.f, a1_2 = 0.f, a1_3 = 0.f, a1_4 = 0.f,
           a1_5 = 0.f, a1_6 = 0.f, a1_7 = 0.f, a1_8 = 0.f;
    float4 b4_0 = F40, b4_1 = F40, b4_2 = F40, b4_3 = F40, b4_4 = F40,
           b4_5 = F40, b4_6 = F40, b4_7 = F40, b4_8 = F40;
    float  b1_0 = 0.f, b1_1 = 0.f, b1_2 = 0.f, b1_3 = 0.f, b1_4 = 0.f,
           b1_5 = 0.f, b1_6 = 0.f, b1_7 = 0.f, b1_8 = 0.f;
    float4 runA4 = F40, runB4 = F40;
    float  runA1 = 0.f, runB1 = 0.f;
    float  acc = 0.f;

#define EMIT(RR4, RR1) do {                                                 \
        const float inv_ = 1.0f / 729.0f;                                   \
        const float mI_ = (RR4).x * inv_, mJ_ = (RR4).y * inv_;             \
        const float vI_ = (RR4).z * inv_ - mI_ * mI_;                       \
        const float vJ_ = (RR4).w * inv_ - mJ_ * mJ_;                       \
        const float cIJ_ = (RR1) * inv_ - mI_ * mJ_;                        \
        acc += (cIJ_ * cIJ_) / (vI_ * vJ_ + 1e-5f);                         \
    } while (0)

#define YSTEP(P, K) do { if (yrole) {                                       \
        const int pb_ = (P) & 1;                                            \
        const float4 q0_ = Q4[pb_][tyt    ][tx];                            \
        const float4 q1_ = Q4[pb_][tyt + 1][tx];                            \
        const float4 q2_ = Q4[pb_][tyt + 2][tx];                            \
        const float4 q3_ = Q4[pb_][tyt + 3][tx];                            \
        const float4 q4_ = Q4[pb_][tyt + 4][tx];                            \
        const float4 r8_ = R4[pb_][yA + 8][tx];                             \
        const float4 r1_ = R4[pb_][yA + 1][tx];                             \
        const float q0s_ = Q1[pb_][tyt    ][tx];                            \
        const float q1s_ = Q1[pb_][tyt + 1][tx];                            \
        const float q2s_ = Q1[pb_][tyt + 2][tx];                            \
        const float q3s_ = Q1[pb_][tyt + 3][tx];                            \
        const float q4s_ = Q1[pb_][tyt + 4][tx];                            \
        const float r8s_ = R1[pb_][yA + 8][tx];                             \
        const float r1s_ = R1[pb_][yA + 1][tx];                             \
        const float4 M4_ = f4add(q1_, f4add(q2_, q3_));                     \
        const float  M1_ = q1s_ + q2s_ + q3s_;                              \
        const float4 sA4 = f4add(f4add(q0_, M4_), r8_);                     \
        const float  sA1 = q0s_ + M1_ + r8s_;                               \
        const float4 sB4 = f4add(f4add(M4_, q4_), r1_);                     \
        const float  sB1 = M1_ + q4s_ + r1s_;                               \
        runA4 = f4add(runA4, f4sub(sA4, a4_##K));   a4_##K = sA4;           \
        runA1 += sA1 - a1_##K;                      a1_##K = sA1;           \
        runB4 = f4add(runB4, f4sub(sB4, b4_##K));   b4_##K = sB4;           \
        runB1 += sB1 - b1_##K;                      b1_##K = sB1;           \
        if ((P) >= 2 * RAD) { EMIT(runA4, runA1); EMIT(runB4, runB1); }     \
    } } while (0)

#define BODY(K) { YSTEP(idx - 1, K); XPHASE(idx); LOAD(idx + 1);            \
                  LDS_BARRIER(); ++idx; }

    // Pipeline: [y(idx-1) | x(idx) | load(idx+1) | lds-barrier] per slice.
    LOAD(0);
    XPHASE(0);
    LOAD(1);
    LDS_BARRIER();

    int idx = 1;
    #pragma unroll 1
    for (int g = 0; g < 6; ++g) {          // P = idx-1 = 0..53, K = P%9
        BODY(0) BODY(1) BODY(2) BODY(3) BODY(4)
        BODY(5) BODY(6) BODY(7) BODY(8)
    }
    BODY(0)                                // P = 54 -> K 0
    YSTEP(NSL - 1, 1);                     // P = 55 -> 55%9 = 1
#undef BODY
#undef YSTEP
#undef EMIT

    // Block reduction: wave shuffle -> LDS -> one double atomic.
    float v = acc;
    #pragma unroll
    for (int off = 32; off >= 1; off >>= 1)
        v += __shfl_down(v, off, 64);
    const int lane = tid & 63;
    const int wid  = tid >> 6;
    if (lane == 0) red[wid] = v;
    __syncthreads();
    if (tid == 0) {
        atomicAdd(ws, (double)(red[0] + red[1] + red[2] + red[3]));
    }
}

extern "C" void kernel_launch(void* const* d_in, const int* in_sizes, int n_in,
                              void* d_out, int out_size, void* d_ws, size_t ws_size,
                              hipStream_t stream) {
    const float* I = (const float*)d_in[0];   // y_pred
    const float* J = (const float*)d_in[1];   // y_true
    double* ws = (double*)d_ws;
    float* out = (float*)d_out;

    hipLaunchKernelGGL(ncc_init, dim3(1), dim3(1), 0, stream, ws);

    hipLaunchKernelGGL(ncc_main, dim3(768), dim3(NTHR), 0, stream, I, J, ws);

    hipLaunchKernelGGL(ncc_final, dim3(1), dim3(1), 0, stream, ws, out);
}

// Round 9
// 306.758 us; speedup vs baseline: 1.0570x; 1.0570x over previous
//
#include <hip/hip_runtime.h>

// NCC loss: five 9x9x9 box sums (I, J, I^2, J^2, I*J), stride 1, pad 4,
// count_include_pad (divisor 729), ncc = cov^2/(varI*varJ+eps), out = -mean.
// Shapes fixed: [2,1,192,192,192] fp32.
//
// R9: WAVE-AUTONOMOUS blocks -- 64 threads = 1 wave, tile 16x8, KZ=48,
// grid 2304 = exactly 9 waves/CU (zero tail), ZERO barriers: intra-wave
// LDS producer->consumer is ordered by program order + s_waitcnt lgkmcnt(0)
// (DS ops of one wave commit in issue order). This removes R7's 40
// per-slice all-wave rendezvous + vmcnt-free drains (~45us of stall).
// All lanes carry both roles with R7's proven register picture:
// x-task = (row 0..15, quad 0..3) sliding windows from direct-global
// float4 loads; y = 2 adjacent outputs/lane with named-scalar z-rings.
// XCD swizzle: 8 patches of 6x6 tiles; entire grid co-resident.

#define S    192
#define SS   (S * S)
#define TW   16                  // tile width  (x outputs)
#define TH   8                   // tile height (y outputs)
#define KZ   48
#define RAD  4
#define WIN  9
#define NSL  (KZ + 2 * RAD)      // 56
#define HXR  (TH + 2 * RAD)      // 16 halo rows
#define XSW  17                  // R4 row stride (float4)
#define NVOX (2.0 * S * S * S)

// Intra-wave LDS fence: commit this wave's DS writes before later DS reads.
// No s_barrier -- single-wave block.
#define LDS_FENCE() __asm__ __volatile__("s_waitcnt lgkmcnt(0)" ::: "memory")

__global__ void ncc_init(double* ws) { ws[0] = 0.0; }

__global__ void ncc_final(const double* __restrict__ ws, float* __restrict__ out) {
    out[0] = (float)(-ws[0] / NVOX);
}

__device__ __forceinline__ float4 f4add(float4 a, float4 b) {
    return make_float4(a.x + b.x, a.y + b.y, a.z + b.z, a.w + b.w);
}
__device__ __forceinline__ float4 f4sub(float4 a, float4 b) {
    return make_float4(a.x - b.x, a.y - b.y, a.z - b.z, a.w - b.w);
}

__global__ __launch_bounds__(64, 3) void ncc_main(const float* __restrict__ I,
                                                  const float* __restrict__ J,
                                                  double* __restrict__ ws) {
    // LDS ~11.3 KB per wave-block: R4 2*16*17*16 + R1 2*16*5*16
    __shared__ float4 R4[2][HXR][XSW];    // (sI, sJ, sI2, sJ2)
    __shared__ float4 R1q[2][HXR][5];     // sIJ rows: 20 floats, 16B-aligned

    const int lane = threadIdx.x;         // 0..63

    // XCD swizzle: 2304 blocks; id&7 = XCD owns a 6x6-tile patch (96x48 px)
    // x all 4 z-chunks x 2 batches. Whole grid co-resident (9 waves/CU).
    const int id  = blockIdx.x;           // 0..2303
    const int xcd = id & 7;
    const int q0  = id >> 3;              // 0..287
    const int t   = q0 % 36;
    const int zz  = q0 / 36;              // 0..7
    const int bx  = (xcd & 1) * 6 + t % 6;      // 0..11
    const int by  = (xcd >> 1) * 6 + t / 6;     // 0..23
    const int zc  = zz & 3;
    const int b   = zz >> 2;
    const int x0 = bx * TW, y0 = by * TH, z0 = zc * KZ;

    const float* Ib = I + (size_t)b * S * SS;
    const float* Jb = J + (size_t)b * S * SS;

    // ---- x-task (all 64 lanes): row r 0..15, quad q 0..3 -> 4 x-outputs
    //      from 12 input cols (3 float4 chunks, each all/none valid) ----
    const int  xr  = lane >> 2;           // 0..15
    const int  xq  = lane & 3;            // 0..3
    const int  gy  = y0 - RAD + xr;
    const bool gyv = ((unsigned)gy < (unsigned)S);
    const int  c0  = x0 + 4 * xq - RAD;
    const bool cv0 = gyv && ((unsigned)(c0)     < (unsigned)S);
    const bool cv1 = gyv && ((unsigned)(c0 + 4) < (unsigned)S);
    const bool cv2 = gyv && ((unsigned)(c0 + 8) < (unsigned)S);
    const ptrdiff_t rowoff = gyv ? ((ptrdiff_t)gy * S + c0) : 0;

    float4 li0, li1, li2, lj0, lj1, lj2;  // 24 regs staging

    auto LOAD = [&](int p) {
        li0 = li1 = li2 = lj0 = lj1 = lj2 = make_float4(0.f, 0.f, 0.f, 0.f);
        if (p < NSL) {
            const int zi = z0 - RAD + p;
            if ((unsigned)zi < (unsigned)S) {
                const float* rI = Ib + (size_t)zi * SS + rowoff;
                const float* rJ = Jb + (size_t)zi * SS + rowoff;
                if (cv0) { li0 = *(const float4*)(rI);     lj0 = *(const float4*)(rJ); }
                if (cv1) { li1 = *(const float4*)(rI + 4); lj1 = *(const float4*)(rJ + 4); }
                if (cv2) { li2 = *(const float4*)(rI + 8); lj2 = *(const float4*)(rJ + 8); }
            }
        }
    };

    auto XPHASE = [&](int p) {
        const float iv[12] = { li0.x, li0.y, li0.z, li0.w,
                               li1.x, li1.y, li1.z, li1.w,
                               li2.x, li2.y, li2.z, li2.w };
        const float jv[12] = { lj0.x, lj0.y, lj0.z, lj0.w,
                               lj1.x, lj1.y, lj1.z, lj1.w,
                               lj2.x, lj2.y, lj2.z, lj2.w };
        float a = 0.f, bb = 0.f, c = 0.f, d = 0.f, e = 0.f;
        #pragma unroll
        for (int m = 0; m < WIN; ++m) {
            a += iv[m];
            bb += jv[m];
            c = fmaf(iv[m], iv[m], c);
            d = fmaf(jv[m], jv[m], d);
            e = fmaf(iv[m], jv[m], e);
        }
        const int cb = p & 1;
        float e0 = e, e1, e2, e3;
        {   // k = 1..3 slides
            a += iv[9]  - iv[0];  bb += jv[9]  - jv[0];
            c += fmaf(iv[9],  iv[9],  -iv[0] * iv[0]);
            d += fmaf(jv[9],  jv[9],  -jv[0] * jv[0]);
            e += fmaf(iv[9],  jv[9],  -iv[0] * jv[0]);
            R4[cb][xr][4 * xq + 1] = make_float4(a, bb, c, d);  e1 = e;
            a += iv[10] - iv[1];  bb += jv[10] - jv[1];
            c += fmaf(iv[10], iv[10], -iv[1] * iv[1]);
            d += fmaf(jv[10], jv[10], -jv[1] * jv[1]);
            e += fmaf(iv[10], jv[10], -iv[1] * jv[1]);
            R4[cb][xr][4 * xq + 2] = make_float4(a, bb, c, d);  e2 = e;
            a += iv[11] - iv[2];  bb += jv[11] - jv[2];
            c += fmaf(iv[11], iv[11], -iv[2] * iv[2]);
            d += fmaf(jv[11], jv[11], -jv[2] * jv[2]);
            e += fmaf(iv[11], jv[11], -iv[2] * jv[2]);
            R4[cb][xr][4 * xq + 3] = make_float4(a, bb, c, d);  e3 = e;
        }
        // k=0 store (recompute window-0 values were consumed first):
        {
            float a0 = 0.f, b0 = 0.f, c0s = 0.f, d0 = 0.f;
            #pragma unroll
            for (int m = 0; m < WIN; ++m) {
                a0 += iv[m];  b0 += jv[m];
                c0s = fmaf(iv[m], iv[m], c0s);
                d0 = fmaf(jv[m], jv[m], d0);
            }
            R4[cb][xr][4 * xq + 0] = make_float4(a0, b0, c0s, d0);
        }
        R1q[cb][xr][xq] = make_float4(e0, e1, e2, e3);
    };

    // ---- y-role (all 64 lanes): outputs (tx, yA) and (tx, yA+1) ----
    const int tx  = lane & 15;
    const int tyt = lane >> 4;            // 0..3
    const int yA  = 2 * tyt;              // 0,2,4,6; taps rows yA..yA+9 <= 15

    // z-rings as NAMED scalars (spill-proof, R6/R7-proven).
    const float4 F40 = make_float4(0.f, 0.f, 0.f, 0.f);
    float4 a4_0 = F40, a4_1 = F40, a4_2 = F40, a4_3 = F40, a4_4 = F40,
           a4_5 = F40, a4_6 = F40, a4_7 = F40, a4_8 = F40;
    float  a1_0 = 0.f, a1_1 = 0.f, a1_2 = 0.f, a1_3 = 0.f, a1_4 = 0.f,
           a1_5 = 0.f, a1_6 = 0.f, a1_7 = 0.f, a1_8 = 0.f;
    float4 b4_0 = F40, b4_1 = F40, b4_2 = F40, b4_3 = F40, b4_4 = F40,
           b4_5 = F40, b4_6 = F40, b4_7 = F40, b4_8 = F40;
    float  b1_0 = 0.f, b1_1 = 0.f, b1_2 = 0.f, b1_3 = 0.f, b1_4 = 0.f,
           b1_5 = 0.f, b1_6 = 0.f, b1_7 = 0.f, b1_8 = 0.f;
    float4 runA4 = F40, runB4 = F40;
    float  runA1 = 0.f, runB1 = 0.f;
    float  acc = 0.f;

    const float* R1f0 = (const float*)&R1q[0][0][0];
    const float* R1f1 = (const float*)&R1q[1][0][0];

#define EMIT(RR4, RR1) do {                                                 \
        const float inv_ = 1.0f / 729.0f;                                   \
        const float mI_ = (RR4).x * inv_, mJ_ = (RR4).y * inv_;             \
        const float vI_ = (RR4).z * inv_ - mI_ * mI_;                       \
        const float vJ_ = (RR4).w * inv_ - mJ_ * mJ_;                       \
        const float cIJ_ = (RR1) * inv_ - mI_ * mJ_;                        \
        acc += (cIJ_ * cIJ_) / (vI_ * vJ_ + 1e-5f);                         \
    } while (0)

#define YSTEP(P, K) do {                                                    \
        const int pb_ = (P) & 1;                                            \
        const float* R1f_ = pb_ ? R1f1 : R1f0;                              \
        float4 t0_4 = R4[pb_][yA][tx];                                      \
        float  t0_1 = R1f_[20 * yA + tx];                                   \
        float4 s4 = t0_4;                                                   \
        float  s1 = t0_1;                                                   \
        _Pragma("unroll")                                                   \
        for (int j_ = 1; j_ < WIN; ++j_) {                                  \
            s4 = f4add(s4, R4[pb_][yA + j_][tx]);                           \
            s1 += R1f_[20 * (yA + j_) + tx];                                \
        }                                                                   \
        const float4 t9_4 = R4[pb_][yA + WIN][tx];                          \
        const float  t9_1 = R1f_[20 * (yA + WIN) + tx];                     \
        const float4 sB4 = f4add(f4sub(s4, t0_4), t9_4);                    \
        const float  sB1 = s1 - t0_1 + t9_1;                                \
        runA4 = f4add(runA4, f4sub(s4, a4_##K));   a4_##K = s4;             \
        runA1 += s1 - a1_##K;                      a1_##K = s1;             \
        runB4 = f4add(runB4, f4sub(sB4, b4_##K));  b4_##K = sB4;            \
        runB1 += sB1 - b1_##K;                     b1_##K = sB1;            \
        if ((P) >= 2 * RAD) { EMIT(runA4, runA1); EMIT(runB4, runB1); }     \
    } while (0)

#define BODY(K) { YSTEP(idx - 1, K); XPHASE(idx); LOAD(idx + 1);            \
                  LDS_FENCE(); ++idx; }

    // Pipeline per slice: [y(idx-1) | x(idx) | load(idx+1) | lds-fence].
    LOAD(0);
    XPHASE(0);
    LOAD(1);
    LDS_FENCE();

    int idx = 1;
    #pragma unroll 1
    for (int g = 0; g < 6; ++g) {          // P = idx-1 = 0..53, K = P%9
        BODY(0) BODY(1) BODY(2) BODY(3) BODY(4)
        BODY(5) BODY(6) BODY(7) BODY(8)
    }
    BODY(0)                                // P = 54 -> K = 0
    YSTEP(NSL - 1, 1);                     // P = 55 -> 55%9 = 1
#undef BODY
#undef YSTEP
#undef EMIT

    // Wave reduction -> one double atomic (single-wave block, no LDS needed).
    float v = acc;
    #pragma unroll
    for (int off = 32; off >= 1; off >>= 1)
        v += __shfl_down(v, off, 64);
    if (lane == 0) {
        atomicAdd(ws, (double)v);
    }
}

extern "C" void kernel_launch(void* const* d_in, const int* in_sizes, int n_in,
                              void* d_out, int out_size, void* d_ws, size_t ws_size,
                              hipStream_t stream) {
    const float* I = (const float*)d_in[0];   // y_pred
    const float* J = (const float*)d_in[1];   // y_true
    double* ws = (double*)d_ws;
    float* out = (float*)d_out;

    hipLaunchKernelGGL(ncc_init, dim3(1), dim3(1), 0, stream, ws);

    hipLaunchKernelGGL(ncc_main, dim3(2304), dim3(64), 0, stream, I, J, ws);

    hipLaunchKernelGGL(ncc_final, dim3(1), dim3(1), 0, stream, ws, out);
}

// Round 10
// 301.250 us; speedup vs baseline: 1.0763x; 1.0183x over previous
//
#include <hip/hip_runtime.h>

// NCC loss: five 9x9x9 box sums (I, J, I^2, J^2, I*J), stride 1, pad 4,
// count_include_pad (divisor 729), ncc = cov^2/(varI*varJ+eps), out = -mean.
// Shapes fixed: [2,1,192,192,192] fp32.
//
// R10 = R9 (wave-autonomous, zero-barrier) with the spill trigger removed:
// __launch_bounds__(64) ONLY -- every round compiled with min-waves=3
// (VGPR cap 170) spilled the z-rings to scratch (R5/R8/R9: VGPR=84,
// WRITE 147-270MB); cap-256 builds (R6/R7) allocated 128 clean. The
// barrier-free theory was never actually tested.
//  - 64 thr = 1 wave per block, tile 16x8, KZ=48, grid 2304 = 9 waves/CU,
//    zero tail, whole grid co-resident.
//  - NO s_barrier anywhere: intra-wave LDS producer->consumer ordered by
//    the wave's in-order DS issue + s_waitcnt lgkmcnt(0).
//  - x-task: (row 0..15, quad 0..3) sliding windows from direct-global
//    float4 loads; y: 2 adjacent outputs/lane, named-scalar z-rings.
//  - XCD swizzle: 8 patches of 6x6 tiles (L2-local halo re-reads).

#define S    192
#define SS   (S * S)
#define TW   16                  // tile width  (x outputs)
#define TH   8                   // tile height (y outputs)
#define KZ   48
#define RAD  4
#define WIN  9
#define NSL  (KZ + 2 * RAD)      // 56
#define HXR  (TH + 2 * RAD)      // 16 halo rows
#define XSW  17                  // R4 row stride (float4)
#define NVOX (2.0 * S * S * S)

// Intra-wave LDS fence (single-wave block; no s_barrier needed).
#define LDS_FENCE() __asm__ __volatile__("s_waitcnt lgkmcnt(0)" ::: "memory")

__global__ void ncc_init(double* ws) { ws[0] = 0.0; }

__global__ void ncc_final(const double* __restrict__ ws, float* __restrict__ out) {
    out[0] = (float)(-ws[0] / NVOX);
}

__device__ __forceinline__ float4 f4add(float4 a, float4 b) {
    return make_float4(a.x + b.x, a.y + b.y, a.z + b.z, a.w + b.w);
}
__device__ __forceinline__ float4 f4sub(float4 a, float4 b) {
    return make_float4(a.x - b.x, a.y - b.y, a.z - b.z, a.w - b.w);
}

__global__ __launch_bounds__(64) void ncc_main(const float* __restrict__ I,
                                               const float* __restrict__ J,
                                               double* __restrict__ ws) {
    // LDS ~11.3 KB per wave-block: R4 2*16*17*16 + R1 2*16*5*16
    __shared__ float4 R4[2][HXR][XSW];    // (sI, sJ, sI2, sJ2)
    __shared__ float4 R1q[2][HXR][5];     // sIJ rows: 20 floats, 16B-aligned

    const int lane = threadIdx.x;         // 0..63

    // XCD swizzle: id&7 = XCD owns a 6x6-tile patch (96x48 px) x 4 z x 2 b.
    const int id  = blockIdx.x;           // 0..2303
    const int xcd = id & 7;
    const int q0  = id >> 3;              // 0..287
    const int t   = q0 % 36;
    const int zz  = q0 / 36;              // 0..7
    const int bx  = (xcd & 1) * 6 + t % 6;      // 0..11
    const int by  = (xcd >> 1) * 6 + t / 6;     // 0..23
    const int zc  = zz & 3;
    const int b   = zz >> 2;
    const int x0 = bx * TW, y0 = by * TH, z0 = zc * KZ;

    const float* Ib = I + (size_t)b * S * SS;
    const float* Jb = J + (size_t)b * S * SS;

    // ---- x-task (all 64 lanes): row r 0..15, quad q 0..3 -> 4 x-outputs
    //      from 12 input cols (3 float4 chunks, each all/none valid) ----
    const int  xr  = lane >> 2;           // 0..15
    const int  xq  = lane & 3;            // 0..3
    const int  gy  = y0 - RAD + xr;
    const bool gyv = ((unsigned)gy < (unsigned)S);
    const int  c0  = x0 + 4 * xq - RAD;
    const bool cv0 = gyv && ((unsigned)(c0)     < (unsigned)S);
    const bool cv1 = gyv && ((unsigned)(c0 + 4) < (unsigned)S);
    const bool cv2 = gyv && ((unsigned)(c0 + 8) < (unsigned)S);
    const ptrdiff_t rowoff = gyv ? ((ptrdiff_t)gy * S + c0) : 0;

    float4 li0, li1, li2, lj0, lj1, lj2;  // 24 regs staging

    auto LOAD = [&](int p) {
        li0 = li1 = li2 = lj0 = lj1 = lj2 = make_float4(0.f, 0.f, 0.f, 0.f);
        if (p < NSL) {
            const int zi = z0 - RAD + p;
            if ((unsigned)zi < (unsigned)S) {
                const float* rI = Ib + (size_t)zi * SS + rowoff;
                const float* rJ = Jb + (size_t)zi * SS + rowoff;
                if (cv0) { li0 = *(const float4*)(rI);     lj0 = *(const float4*)(rJ); }
                if (cv1) { li1 = *(const float4*)(rI + 4); lj1 = *(const float4*)(rJ + 4); }
                if (cv2) { li2 = *(const float4*)(rI + 8); lj2 = *(const float4*)(rJ + 8); }
            }
        }
    };

    auto XPHASE = [&](int p) {
        const float iv[12] = { li0.x, li0.y, li0.z, li0.w,
                               li1.x, li1.y, li1.z, li1.w,
                               li2.x, li2.y, li2.z, li2.w };
        const float jv[12] = { lj0.x, lj0.y, lj0.z, lj0.w,
                               lj1.x, lj1.y, lj1.z, lj1.w,
                               lj2.x, lj2.y, lj2.z, lj2.w };
        float a = 0.f, bb = 0.f, c = 0.f, d = 0.f, e = 0.f;
        #pragma unroll
        for (int m = 0; m < WIN; ++m) {
            a += iv[m];
            bb += jv[m];
            c = fmaf(iv[m], iv[m], c);
            d = fmaf(jv[m], jv[m], d);
            e = fmaf(iv[m], jv[m], e);
        }
        const int cb = p & 1;
        R4[cb][xr][4 * xq + 0] = make_float4(a, bb, c, d);
        const float e0 = e;
        a += iv[9]  - iv[0];  bb += jv[9]  - jv[0];
        c += fmaf(iv[9],  iv[9],  -iv[0] * iv[0]);
        d += fmaf(jv[9],  jv[9],  -jv[0] * jv[0]);
        e += fmaf(iv[9],  jv[9],  -iv[0] * jv[0]);
        R4[cb][xr][4 * xq + 1] = make_float4(a, bb, c, d);
        const float e1 = e;
        a += iv[10] - iv[1];  bb += jv[10] - jv[1];
        c += fmaf(iv[10], iv[10], -iv[1] * iv[1]);
        d += fmaf(jv[10], jv[10], -jv[1] * jv[1]);
        e += fmaf(iv[10], jv[10], -iv[1] * jv[1]);
        R4[cb][xr][4 * xq + 2] = make_float4(a, bb, c, d);
        const float e2 = e;
        a += iv[11] - iv[2];  bb += jv[11] - jv[2];
        c += fmaf(iv[11], iv[11], -iv[2] * iv[2]);
        d += fmaf(jv[11], jv[11], -jv[2] * jv[2]);
        e += fmaf(iv[11], jv[11], -iv[2] * jv[2]);
        R4[cb][xr][4 * xq + 3] = make_float4(a, bb, c, d);
        R1q[cb][xr][xq] = make_float4(e0, e1, e2, e);
    };

    // ---- y-role (all 64 lanes): outputs (tx, yA) and (tx, yA+1) ----
    const int tx  = lane & 15;
    const int tyt = lane >> 4;            // 0..3
    const int yA  = 2 * tyt;              // 0,2,4,6; taps rows yA..yA+9 <= 15

    // z-rings as NAMED scalars (spill-proof given cap-256).
    const float4 F40 = make_float4(0.f, 0.f, 0.f, 0.f);
    float4 a4_0 = F40, a4_1 = F40, a4_2 = F40, a4_3 = F40, a4_4 = F40,
           a4_5 = F40, a4_6 = F40, a4_7 = F40, a4_8 = F40;
    float  a1_0 = 0.f, a1_1 = 0.f, a1_2 = 0.f, a1_3 = 0.f, a1_4 = 0.f,
           a1_5 = 0.f, a1_6 = 0.f, a1_7 = 0.f, a1_8 = 0.f;
    float4 b4_0 = F40, b4_1 = F40, b4_2 = F40, b4_3 = F40, b4_4 = F40,
           b4_5 = F40, b4_6 = F40, b4_7 = F40, b4_8 = F40;
    float  b1_0 = 0.f, b1_1 = 0.f, b1_2 = 0.f, b1_3 = 0.f, b1_4 = 0.f,
           b1_5 = 0.f, b1_6 = 0.f, b1_7 = 0.f, b1_8 = 0.f;
    float4 runA4 = F40, runB4 = F40;
    float  runA1 = 0.f, runB1 = 0.f;
    float  acc = 0.f;

    const float* R1f0 = (const float*)&R1q[0][0][0];
    const float* R1f1 = (const float*)&R1q[1][0][0];

#define EMIT(RR4, RR1) do {                                                 \
        const float inv_ = 1.0f / 729.0f;                                   \
        const float mI_ = (RR4).x * inv_, mJ_ = (RR4).y * inv_;             \
        const float vI_ = (RR4).z * inv_ - mI_ * mI_;                       \
        const float vJ_ = (RR4).w * inv_ - mJ_ * mJ_;                       \
        const float cIJ_ = (RR1) * inv_ - mI_ * mJ_;                        \
        acc += (cIJ_ * cIJ_) / (vI_ * vJ_ + 1e-5f);                         \
    } while (0)

#define YSTEP(P, K) do {                                                    \
        const int pb_ = (P) & 1;                                            \
        const float* R1f_ = pb_ ? R1f1 : R1f0;                              \
        float4 t0_4 = R4[pb_][yA][tx];                                      \
        float  t0_1 = R1f_[20 * yA + tx];                                   \
        float4 s4 = t0_4;                                                   \
        float  s1 = t0_1;                                                   \
        _Pragma("unroll")                                                   \
        for (int j_ = 1; j_ < WIN; ++j_) {                                  \
            s4 = f4add(s4, R4[pb_][yA + j_][tx]);                           \
            s1 += R1f_[20 * (yA + j_) + tx];                                \
        }                                                                   \
        const float4 t9_4 = R4[pb_][yA + WIN][tx];                          \
        const float  t9_1 = R1f_[20 * (yA + WIN) + tx];                     \
        const float4 sB4 = f4add(f4sub(s4, t0_4), t9_4);                    \
        const float  sB1 = s1 - t0_1 + t9_1;                                \
        runA4 = f4add(runA4, f4sub(s4, a4_##K));   a4_##K = s4;             \
        runA1 += s1 - a1_##K;                      a1_##K = s1;             \
        runB4 = f4add(runB4, f4sub(sB4, b4_##K));  b4_##K = sB4;            \
        runB1 += sB1 - b1_##K;                     b1_##K = sB1;            \
        if ((P) >= 2 * RAD) { EMIT(runA4, runA1); EMIT(runB4, runB1); }     \
    } while (0)

#define BODY(K) { YSTEP(idx - 1, K); XPHASE(idx); LOAD(idx + 1);            \
                  LDS_FENCE(); ++idx; }

    // Pipeline per slice: [y(idx-1) | x(idx) | load(idx+1) | lds-fence].
    LOAD(0);
    XPHASE(0);
    LOAD(1);
    LDS_FENCE();

    int idx = 1;
    #pragma unroll 1
    for (int g = 0; g < 6; ++g) {          // P = idx-1 = 0..53, K = P%9
        BODY(0) BODY(1) BODY(2) BODY(3) BODY(4)
        BODY(5) BODY(6) BODY(7) BODY(8)
    }
    BODY(0)                                // P = 54 -> K = 0
    YSTEP(NSL - 1, 1);                     // P = 55 -> 55%9 = 1
#undef BODY
#undef YSTEP
#undef EMIT

    // Wave reduction -> one double atomic (single-wave block).
    float v = acc;
    #pragma unroll
    for (int off = 32; off >= 1; off >>= 1)
        v += __shfl_down(v, off, 64);
    if (lane == 0) {
        atomicAdd(ws, (double)v);
    }
}

extern "C" void kernel_launch(void* const* d_in, const int* in_sizes, int n_in,
                              void* d_out, int out_size, void* d_ws, size_t ws_size,
                              hipStream_t stream) {
    const float* I = (const float*)d_in[0];   // y_pred
    const float* J = (const float*)d_in[1];   // y_true
    double* ws = (double*)d_ws;
    float* out = (float*)d_out;

    hipLaunchKernelGGL(ncc_init, dim3(1), dim3(1), 0, stream, ws);

    hipLaunchKernelGGL(ncc_main, dim3(2304), dim3(64), 0, stream, I, J, ws);

    hipLaunchKernelGGL(ncc_final, dim3(1), dim3(1), 0, stream, ws, out);
}

// Round 11
// 227.395 us; speedup vs baseline: 1.4259x; 1.3248x over previous
//
#include <hip/hip_runtime.h>

// NCC loss: five 9x9x9 box sums (I, J, I^2, J^2, I*J), stride 1, pad 4,
// count_include_pad (divisor 729), ncc = cov^2/(varI*varJ+eps), out = -mean.
// Shapes fixed: [2,1,192,192,192] fp32.
//
// R11 = R7 (champion, 109us) with the grid-imbalance removed:
//  - tile 16x24, KZ=48 -> grid 768 = EXACTLY 3 blocks/CU (R7's 864 gave 96
//    CUs a 4th round = ~19% tail). Work totals are geometry-invariant.
//  - uniform roles (NOT R8's register-doubling role split): x-tasks on
//    threads 128..255 (32 rows x 4 quads), y on threads 0..191 (2 adjacent
//    outputs, B = A - t0 + t9).
//  - carried, all proven: named-scalar z-rings ((256,2) only -- every
//    min-waves>=3 build spilled), LDS-only barrier (lgkmcnt+s_barrier, no
//    vmcnt drain), direct-global float4 x-phase with e0..e3 slide (R10),
//    float4 R1 write / stride-20 scalar R1 read (exact 2-way banks = free),
//    XCD swizzle.
// R10 falsified wave-autonomous blocks: 9 waves/CU of serial chains ->
// VALUBusy 21%, 213us. Latency hiding needs the 16-waves/CU mix.

#define S    192
#define SS   (S * S)
#define TX   16
#define YT   24                  // y-tile
#define NTHR 256
#define KZ   48
#define RAD  4
#define WIN  9
#define NSL  (KZ + 2 * RAD)      // 56
#define HXR  (YT + 2 * RAD)      // 32 halo rows
#define XSW  17                  // R4 row stride (float4)
#define NVOX (2.0 * S * S * S)

// LDS-only barrier: no vmcnt drain -> global prefetch stays in flight.
#define LDS_BARRIER() __asm__ __volatile__("s_waitcnt lgkmcnt(0)\n\ts_barrier" ::: "memory")

__global__ void ncc_init(double* ws) { ws[0] = 0.0; }

__global__ void ncc_final(const double* __restrict__ ws, float* __restrict__ out) {
    out[0] = (float)(-ws[0] / NVOX);
}

__device__ __forceinline__ float4 f4add(float4 a, float4 b) {
    return make_float4(a.x + b.x, a.y + b.y, a.z + b.z, a.w + b.w);
}
__device__ __forceinline__ float4 f4sub(float4 a, float4 b) {
    return make_float4(a.x - b.x, a.y - b.y, a.z - b.z, a.w - b.w);
}

__global__ __launch_bounds__(NTHR, 2) void ncc_main(const float* __restrict__ I,
                                                    const float* __restrict__ J,
                                                    double* __restrict__ ws) {
    // LDS ~22.6 KB: R4 2*32*17*16 + R1q 2*32*5*16 + red
    __shared__ float4 R4[2][HXR][XSW];    // (sI, sJ, sI2, sJ2)
    __shared__ float4 R1q[2][HXR][5];     // sIJ rows: 20 floats each
    __shared__ float  red[4];

    const int tid = threadIdx.x;          // 0..255

    // XCD swizzle over 768 blocks: 12x8 xy-tiles split into 8 patches of 3x4.
    const int id  = blockIdx.x;           // 0..767
    const int xcd = id & 7;
    const int q0  = id >> 3;              // 0..95
    const int t   = q0 % 12;
    const int zb  = q0 / 12;              // 0..7
    const int bx  = (xcd & 3) * 3 + t % 3;      // 0..11
    const int by  = (xcd >> 2) * 4 + t / 3;     // 0..7
    const int zc  = zb & 3;
    const int b   = zb >> 2;
    const int x0 = bx * TX, y0 = by * YT, z0 = zc * KZ;

    const float* Ib = I + (size_t)b * S * SS;
    const float* Jb = J + (size_t)b * S * SS;

    // ---- x-tasks on threads 128..255: (row 0..31, quad 0..3) ----
    const bool xtask = (tid >= 128);
    const int  u   = tid - 128;           // 0..127
    const int  xr  = u >> 2;              // 0..31
    const int  xq  = u & 3;               // 0..3
    const int  gy  = y0 - RAD + xr;
    const bool gyv = xtask && ((unsigned)gy < (unsigned)S);
    const int  c0  = x0 + 4 * xq - RAD;
    const bool cv0 = gyv && ((unsigned)(c0)     < (unsigned)S);
    const bool cv1 = gyv && ((unsigned)(c0 + 4) < (unsigned)S);
    const bool cv2 = gyv && ((unsigned)(c0 + 8) < (unsigned)S);
    const ptrdiff_t rowoff = gyv ? ((ptrdiff_t)gy * S + c0) : 0;

    float4 li0, li1, li2, lj0, lj1, lj2;  // 24 staging regs

    auto LOAD = [&](int p) {
        li0 = li1 = li2 = lj0 = lj1 = lj2 = make_float4(0.f, 0.f, 0.f, 0.f);
        if (p < NSL) {
            const int zi = z0 - RAD + p;
            if ((unsigned)zi < (unsigned)S) {
                const float* rI = Ib + (size_t)zi * SS + rowoff;
                const float* rJ = Jb + (size_t)zi * SS + rowoff;
                if (cv0) { li0 = *(const float4*)(rI);     lj0 = *(const float4*)(rJ); }
                if (cv1) { li1 = *(const float4*)(rI + 4); lj1 = *(const float4*)(rJ + 4); }
                if (cv2) { li2 = *(const float4*)(rI + 8); lj2 = *(const float4*)(rJ + 8); }
            }
        }
    };

    auto XPHASE = [&](int p) {
        if (xtask) {
            const float iv[12] = { li0.x, li0.y, li0.z, li0.w,
                                   li1.x, li1.y, li1.z, li1.w,
                                   li2.x, li2.y, li2.z, li2.w };
            const float jv[12] = { lj0.x, lj0.y, lj0.z, lj0.w,
                                   lj1.x, lj1.y, lj1.z, lj1.w,
                                   lj2.x, lj2.y, lj2.z, lj2.w };
            float a = 0.f, bb = 0.f, c = 0.f, d = 0.f, e = 0.f;
            #pragma unroll
            for (int m = 0; m < WIN; ++m) {
                a += iv[m];
                bb += jv[m];
                c = fmaf(iv[m], iv[m], c);
                d = fmaf(jv[m], jv[m], d);
                e = fmaf(iv[m], jv[m], e);
            }
            const int cb = p & 1;
            R4[cb][xr][4 * xq + 0] = make_float4(a, bb, c, d);
            const float e0 = e;
            a += iv[9]  - iv[0];  bb += jv[9]  - jv[0];
            c += fmaf(iv[9],  iv[9],  -iv[0] * iv[0]);
            d += fmaf(jv[9],  jv[9],  -jv[0] * jv[0]);
            e += fmaf(iv[9],  jv[9],  -iv[0] * jv[0]);
            R4[cb][xr][4 * xq + 1] = make_float4(a, bb, c, d);
            const float e1 = e;
            a += iv[10] - iv[1];  bb += jv[10] - jv[1];
            c += fmaf(iv[10], iv[10], -iv[1] * iv[1]);
            d += fmaf(jv[10], jv[10], -jv[1] * jv[1]);
            e += fmaf(iv[10], jv[10], -iv[1] * jv[1]);
            R4[cb][xr][4 * xq + 2] = make_float4(a, bb, c, d);
            const float e2 = e;
            a += iv[11] - iv[2];  bb += jv[11] - jv[2];
            c += fmaf(iv[11], iv[11], -iv[2] * iv[2]);
            d += fmaf(jv[11], jv[11], -jv[2] * jv[2]);
            e += fmaf(iv[11], jv[11], -iv[2] * jv[2]);
            R4[cb][xr][4 * xq + 3] = make_float4(a, bb, c, d);
            R1q[cb][xr][xq] = make_float4(e0, e1, e2, e);
        }
    };

    // ---- y-role on threads 0..191: outputs (tx, yA), (tx, yA+1) ----
    const bool yrole = (tid < 192);
    const int  tx  = tid & 15;
    const int  tyt = tid >> 4;            // 0..11 valid
    const int  yA  = 2 * tyt;             // 0..22; taps yA..yA+9 <= 31

    // z-rings as NAMED scalars (spill-proof under (256,2); R6/R7-proven).
    const float4 F40 = make_float4(0.f, 0.f, 0.f, 0.f);
    float4 a4_0 = F40, a4_1 = F40, a4_2 = F40, a4_3 = F40, a4_4 = F40,
           a4_5 = F40, a4_6 = F40, a4_7 = F40, a4_8 = F40;
    float  a1_0 = 0.f, a1_1 = 0.f, a1_2 = 0.f, a1_3 = 0.f, a1_4 = 0.f,
           a1_5 = 0.f, a1_6 = 0.f, a1_7 = 0.f, a1_8 = 0.f;
    float4 b4_0 = F40, b4_1 = F40, b4_2 = F40, b4_3 = F40, b4_4 = F40,
           b4_5 = F40, b4_6 = F40, b4_7 = F40, b4_8 = F40;
    float  b1_0 = 0.f, b1_1 = 0.f, b1_2 = 0.f, b1_3 = 0.f, b1_4 = 0.f,
           b1_5 = 0.f, b1_6 = 0.f, b1_7 = 0.f, b1_8 = 0.f;
    float4 runA4 = F40, runB4 = F40;
    float  runA1 = 0.f, runB1 = 0.f;
    float  acc = 0.f;

    const float* R1f0 = (const float*)&R1q[0][0][0];
    const float* R1f1 = (const float*)&R1q[1][0][0];

#define EMIT(RR4, RR1) do {                                                 \
        const float inv_ = 1.0f / 729.0f;                                   \
        const float mI_ = (RR4).x * inv_, mJ_ = (RR4).y * inv_;             \
        const float vI_ = (RR4).z * inv_ - mI_ * mI_;                       \
        const float vJ_ = (RR4).w * inv_ - mJ_ * mJ_;                       \
        const float cIJ_ = (RR1) * inv_ - mI_ * mJ_;                        \
        acc += (cIJ_ * cIJ_) / (vI_ * vJ_ + 1e-5f);                         \
    } while (0)

#define YSTEP(P, K) do { if (yrole) {                                       \
        const int pb_ = (P) & 1;                                            \
        const float* R1f_ = pb_ ? R1f1 : R1f0;                              \
        float4 t0_4 = R4[pb_][yA][tx];                                      \
        float  t0_1 = R1f_[20 * yA + tx];                                   \
        float4 s4 = t0_4;                                                   \
        float  s1 = t0_1;                                                   \
        _Pragma("unroll")                                                   \
        for (int j_ = 1; j_ < WIN; ++j_) {                                  \
            s4 = f4add(s4, R4[pb_][yA + j_][tx]);                           \
            s1 += R1f_[20 * (yA + j_) + tx];                                \
        }                                                                   \
        const float4 t9_4 = R4[pb_][yA + WIN][tx];                          \
        const float  t9_1 = R1f_[20 * (yA + WIN) + tx];                     \
        const float4 sB4 = f4add(f4sub(s4, t0_4), t9_4);                    \
        const float  sB1 = s1 - t0_1 + t9_1;                                \
        runA4 = f4add(runA4, f4sub(s4, a4_##K));   a4_##K = s4;             \
        runA1 += s1 - a1_##K;                      a1_##K = s1;             \
        runB4 = f4add(runB4, f4sub(sB4, b4_##K));  b4_##K = sB4;            \
        runB1 += sB1 - b1_##K;                     b1_##K = sB1;            \
        if ((P) >= 2 * RAD) { EMIT(runA4, runA1); EMIT(runB4, runB1); }     \
    } } while (0)

#define BODY(K) { YSTEP(idx - 1, K); XPHASE(idx); LOAD(idx + 1);            \
                  LDS_BARRIER(); ++idx; }

    // Pipeline per slice: [y(idx-1) | x(idx) | load(idx+1) | lds-barrier].
    LOAD(0);
    XPHASE(0);
    LOAD(1);
    LDS_BARRIER();

    int idx = 1;
    #pragma unroll 1
    for (int g = 0; g < 6; ++g) {          // P = idx-1 = 0..53, K = P%9
        BODY(0) BODY(1) BODY(2) BODY(3) BODY(4)
        BODY(5) BODY(6) BODY(7) BODY(8)
    }
    BODY(0)                                // P = 54 -> K = 0
    YSTEP(NSL - 1, 1);                     // P = 55 -> 55%9 = 1
#undef BODY
#undef YSTEP
#undef EMIT

    // Block reduction: wave shuffle -> LDS -> one double atomic.
    float v = acc;
    #pragma unroll
    for (int off = 32; off >= 1; off >>= 1)
        v += __shfl_down(v, off, 64);
    const int lane = tid & 63;
    const int wid  = tid >> 6;
    if (lane == 0) red[wid] = v;
    __syncthreads();
    if (tid == 0) {
        atomicAdd(ws, (double)(red[0] + red[1] + red[2] + red[3]));
    }
}

extern "C" void kernel_launch(void* const* d_in, const int* in_sizes, int n_in,
                              void* d_out, int out_size, void* d_ws, size_t ws_size,
                              hipStream_t stream) {
    const float* I = (const float*)d_in[0];   // y_pred
    const float* J = (const float*)d_in[1];   // y_true
    double* ws = (double*)d_ws;
    float* out = (float*)d_out;

    hipLaunchKernelGGL(ncc_init, dim3(1), dim3(1), 0, stream, ws);

    hipLaunchKernelGGL(ncc_main, dim3(768), dim3(NTHR), 0, stream, I, J, ws);

    hipLaunchKernelGGL(ncc_final, dim3(1), dim3(1), 0, stream, ws, out);
}